// Round 1
// 518.390 us; speedup vs baseline: 1.1103x; 1.1103x over previous
//
#include <hip/hip_runtime.h>

#define NEG_INF -1e30f

constexpr int BLANKC = 6624;
constexpr int NCLS   = 6625;
constexpr int TT     = 512;
constexpr int LL     = 32;
constexpr int NSLOT  = LL + 1;   // 33: slot 0 = blank, slot 1+j = label j
constexpr int BB     = 32;
constexpr int KPT    = TT / 64;  // 8 timesteps per lane in kernel A

constexpr float L2E = 1.44269504088896340736f;  // log2(e)
constexpr float LN2 = 0.693147180559945309417f; // ln(2)

__device__ __forceinline__ float fast_exp2(float x) {
#if __has_builtin(__builtin_amdgcn_exp2f)
    return __builtin_amdgcn_exp2f(x);     // v_exp_f32 (native base-2)
#else
    return exp2f(x);
#endif
}
__device__ __forceinline__ float fast_log2(float x) {
#if __has_builtin(__builtin_amdgcn_logf)
    return __builtin_amdgcn_logf(x);      // v_log_f32 (native base-2)
#else
    return log2f(x);
#endif
}

// lane i <- lane i-1 (wave_shr:1); lane 0 <- NEG_INF via DPP "old" operand.
// ~4 cy vs ~100 cy for ds_bpermute-based __shfl_up.
__device__ __forceinline__ float dpp_shr1(float x) {
#if __has_builtin(__builtin_amdgcn_update_dpp)
    return __int_as_float(__builtin_amdgcn_update_dpp(
        __float_as_int(NEG_INF), __float_as_int(x),
        0x138 /*wave_shr:1*/, 0xF, 0xF, false));
#else
    float r = __shfl_up(x, 1, 64);
    if ((int)(threadIdx.x & 63) == 0) r = NEG_INF;
    return r;
#endif
}

__device__ __forceinline__ float wave_allmax(float v) {
#pragma unroll
    for (int off = 32; off > 0; off >>= 1)
        v = fmaxf(v, __shfl_xor(v, off, 64));
    return v;
}
__device__ __forceinline__ float wave_allsum(float v) {
#pragma unroll
    for (int off = 32; off > 0; off >>= 1)
        v += __shfl_xor(v, off, 64);
    return v;
}

// ---------------------------------------------------------------------------
// Kernel A: per (batch, slot) log2-softmax over the TIME axis of the one
// class column this slot needs. One wave per column; 4 waves per block.
// Output is BASE-2 log-probabilities (consumed as-is by kernel B).
// ---------------------------------------------------------------------------
__global__ __launch_bounds__(256) void ctc_colnorm(
    const float* __restrict__ x,        // [B, T, C]
    const int*   __restrict__ targets,  // [B, L]
    float*       __restrict__ cols)     // [B, NSLOT, T] (log2 domain)
{
    const int wid  = blockIdx.x * 4 + (threadIdx.x >> 6);
    const int lane = threadIdx.x & 63;
    if (wid >= BB * NSLOT) return;
    const int b    = wid / NSLOT;
    const int slot = wid - b * NSLOT;
    const int c    = (slot == 0) ? BLANKC : targets[b * LL + slot - 1];

    const float* xb = x + (size_t)b * TT * NCLS + c;
    float v[KPT];
    float m = NEG_INF;
#pragma unroll
    for (int k = 0; k < KPT; ++k) {
        v[k] = xb[(size_t)(lane + 64 * k) * NCLS];
        m = fmaxf(m, v[k]);
    }
    m = wave_allmax(m);
    float w[KPT];
    float s = 0.f;
#pragma unroll
    for (int k = 0; k < KPT; ++k) {
        w[k] = (v[k] - m) * L2E;        // base-2 shifted logits
        s += fast_exp2(w[k]);
    }
    s = wave_allsum(s);
    const float ls = fast_log2(s);

    float* cb = cols + (size_t)(b * NSLOT + slot) * TT;
#pragma unroll
    for (int k = 0; k < KPT; ++k) cb[lane + 64 * k] = w[k] - ls;
}

// ---------------------------------------------------------------------------
// Kernel B: alpha recursion, base-2 logsumexp. One wave per batch; lane = state
// s in [0,64). State 64 is computed LANE-LOCALLY: new64 = lse2(a64, alpha_old)
// + eb uses only the lane's own alpha, so lane 63 carries the true value — no
// cross-lane broadcast per step. Emissions are prefetched into registers in
// 32-step chunks (double-buffered), so the recurrence never waits on memory.
// ---------------------------------------------------------------------------
__device__ __forceinline__ void ctc_step(float& alpha, float& a64,
                                         float e, float eb, bool allow) {
    float am1 = dpp_shr1(alpha);            // alpha[s-1] (lane0 -> NEG_INF)
    float am2 = dpp_shr1(am1);              // alpha[s-2] (lane0,1 -> NEG_INF)
    am2 = allow ? am2 : NEG_INF;
    const float aold = alpha;
    const float m  = fmaxf(fmaxf(aold, am1), am2);   // v_max3_f32
    const float r  = fast_exp2(aold - m) + fast_exp2(am1 - m) + fast_exp2(am2 - m);
    const float na = m + fast_log2(r) + e;
    // state-64 (blank sink): 2-way lse with the lane's own alpha
    const float m2   = fmaxf(a64, aold);
    const float r2   = fast_exp2(a64 - m2) + fast_exp2(aold - m2);
    const float na64 = m2 + fast_log2(r2) + eb;
    alpha = na;
    a64   = na64;
}

// load chunk c (32 timesteps) of this lane's emission column into registers
#define LOADC(E, c) do {                                                      \
    const float4* __p = reinterpret_cast<const float4*>(ec + ((c) << 5));     \
    _Pragma("unroll")                                                         \
    for (int k = 0; k < 8; ++k) {                                             \
        float4 __t = __p[k];                                                  \
        E[4*k+0] = __t.x; E[4*k+1] = __t.y;                                   \
        E[4*k+2] = __t.z; E[4*k+3] = __t.w;                                   \
    }                                                                         \
} while (0)

// run steps u0..31 of a chunk. eb (blank emission) = lane 0's value: lane 0 is
// even -> slot 0 -> blank column; v_readfirstlane is off the critical path.
#define CHUNK(E, u0) do {                                                     \
    _Pragma("unroll")                                                         \
    for (int u = (u0); u < 32; ++u) {                                         \
        const float e_  = E[u];                                               \
        const float eb_ = __int_as_float(                                     \
            __builtin_amdgcn_readfirstlane(__float_as_int(E[u])));            \
        ctc_step(alpha, a64, e_, eb_, allow);                                 \
    }                                                                         \
} while (0)

__global__ __launch_bounds__(64) void ctc_alpha(
    const float* __restrict__ cols,     // [B, NSLOT, T] (log2 domain)
    const int*   __restrict__ targets,  // [B, L]
    const int*   __restrict__ input_lengths,
    const int*   __restrict__ target_lengths,
    float*       __restrict__ part)     // [B] per-batch loss
{
    const int b = blockIdx.x;
    const int s = threadIdx.x;          // 0..63 = state index
    const int j = s >> 1;               // label index when s odd
    const bool odd = (s & 1) != 0;

    const int ext_s = odd ? targets[b * LL + j] : BLANKC;
    const bool allow = odd && (ext_s != BLANKC) &&
                       (s == 1 || ext_s != targets[b * LL + j - 1]);

    // this lane's emission column (slot 0 for even lanes = blank)
    const float* ec = cols + ((size_t)b * NSLOT + (odd ? (size_t)(1 + j) : (size_t)0)) * TT;

    const int ilen = input_lengths[b];
    const int tlen = target_lengths[b];
    const int nsteps = min(ilen, TT);   // recursion runs t = 1..nsteps-1; frozen after

    float alpha;
    float a64 = NEG_INF;

    if (nsteps == TT) {
        // fast path: full-length, register double-buffered 32-step chunks
        float eA[32], eB[32];
        LOADC(eA, 0);
        LOADC(eB, 1);
        // init (t=0): alpha[0]=blank@t0 (lane0's col), alpha[1]=label0@t0 (lane1's col)
        alpha = (s < 2) ? eA[0] : NEG_INF;
        CHUNK(eA, 1);                   // chunk 0: steps t=1..31
#pragma unroll 1
        for (int p = 1; p + 1 < 16; p += 2) {   // p = 1,3,...,13
            LOADC(eA, p + 1);           // prefetch while computing chunk p
            CHUNK(eB, 0);               // chunk p
            LOADC(eB, p + 2);           // prefetch while computing chunk p+1
            CHUNK(eA, 0);               // chunk p+1
        }
        CHUNK(eB, 0);                   // chunk 15
    } else {
        // generic path (correctness-only; bench always takes the fast path).
        // Frozen steps (t >= ilen) change nothing, so just stop early.
        const float* bc = cols + (size_t)b * NSLOT * TT;  // blank column
        alpha = (s < 2) ? ec[0] : NEG_INF;
        for (int t = 1; t < nsteps; ++t) {
            const float e  = ec[t];
            const float eb = bc[t];
            ctc_step(alpha, a64, e, eb, allow);
        }
    }

    const int idx1 = 2 * tlen;                    // final blank (may be 64)
    const int idx2 = max(2 * tlen - 1, 0);        // final label (<= 63)
    const float l1 = (idx1 >= 64) ? __shfl(a64, 63, 64) : __shfl(alpha, idx1, 64);
    const float l2 = __shfl(alpha, idx2, 64);
    const float mm = fmaxf(l1, l2);
    const float res2 = mm + fast_log2(fast_exp2(l1 - mm) + fast_exp2(l2 - mm));
    float loss = -LN2 * res2;                     // back to natural-log loss
    if (loss > 1e20f) loss = 0.f;                 // zero_infinity
    loss /= (float)max(tlen, 1);
    if (s == 0) part[b] = loss;
}

// ---------------------------------------------------------------------------
// Kernel C: mean over batch (d_out is poisoned each call -> must write).
// ---------------------------------------------------------------------------
__global__ __launch_bounds__(64) void ctc_reduce(
    const float* __restrict__ part, float* __restrict__ out)
{
    const int lane = threadIdx.x;
    float v = (lane < BB) ? part[lane] : 0.f;
#pragma unroll
    for (int off = 32; off > 0; off >>= 1) v += __shfl_xor(v, off, 64);
    if (lane == 0) out[0] = v / (float)BB;
}

extern "C" void kernel_launch(void* const* d_in, const int* in_sizes, int n_in,
                              void* d_out, int out_size, void* d_ws, size_t ws_size,
                              hipStream_t stream) {
    const float* lp      = (const float*)d_in[0];   // [B, T, C] fp32
    const int*   targets = (const int*)d_in[1];     // [B, L]
    const int*   ilen    = (const int*)d_in[2];     // [B]
    const int*   tlen    = (const int*)d_in[3];     // [B]
    float* out = (float*)d_out;

    constexpr size_t COLS_ELEMS = (size_t)BB * NSLOT * TT;          // 541,696 floats
    float* cols = (float*)d_ws;
    float* part = (float*)d_ws + COLS_ELEMS;

    const int gridA = (BB * NSLOT + 3) / 4;   // 4 waves (columns) per block
    ctc_colnorm<<<gridA, 256, 0, stream>>>(lp, targets, cols);
    ctc_alpha<<<BB, 64, 0, stream>>>(cols, targets, ilen, tlen, part);
    ctc_reduce<<<1, 64, 0, stream>>>(part, out);
}